// Round 2
// baseline (153.276 us; speedup 1.0000x reference)
//
#include <hip/hip_runtime.h>
#include <math.h>

// Problem constants: feat (B=16, C=4, h=128, w=240), MAX_DISP=24,
// output (B,1,1024,1920) fp32.
#define BB 16
#define CC 4
#define HH 128
#define WW 240
#define MAXD 24
#define OH 1024
#define OW 1920

// Fused: cost volume + softmax-expectation + x8 + bilinear align-corners resize.
// One block per (b, y0): computes pred rows y0 and y0+1, x-interpolates both to
// width 1920 in LDS, then writes the ~8 output rows whose floor(oy*sy) == y0.
__global__ __launch_bounds__(256) void fused_kernel(const float* __restrict__ fl,
                                                    const float* __restrict__ fr,
                                                    float* __restrict__ out) {
    const int blk = blockIdx.x;           // b*HH + y0
    const int b = blk >> 7;
    const int y0 = blk & (HH - 1);
    const int y1 = min(y0 + 1, HH - 1);
    const int tid = threadIdx.x;

    __shared__ float sR[2][CC][WW + MAXD - 1];  // zero-padded left by 23
    __shared__ float sP[2][WW];                 // pred rows (already x8 scaled)
    __shared__ float vx[2][OW];                 // x-interpolated pred rows

    const int rows2[2] = {y0, y1};

    // Phase 1: stage right-feature rows into LDS (zero left pad).
    for (int i = tid; i < 2 * CC * WW; i += 256) {
        const int r = i / (CC * WW);
        const int rem = i - r * (CC * WW);
        const int c = rem / WW;
        const int x = rem - c * WW;
        sR[r][c][x + MAXD - 1] = fr[(((size_t)b * CC + c) * HH + rows2[r]) * WW + x];
    }
    for (int i = tid; i < 2 * CC * (MAXD - 1); i += 256) {
        const int r = i / (CC * (MAXD - 1));
        const int rem = i - r * (CC * (MAXD - 1));
        const int c = rem / (MAXD - 1);
        const int x = rem - c * (MAXD - 1);
        sR[r][c][x] = 0.0f;
    }
    __syncthreads();

    // Phase 2: pred rows (cost volume + stabilized softmax expectation, x8).
    for (int j = tid; j < 2 * WW; j += 256) {
        const int r = j / WW;
        const int x = j - r * WW;
        const size_t g = (((size_t)b * CC) * HH + rows2[r]) * WW + x;
        const float l0 = fl[g];
        const float l1 = fl[g + (size_t)HH * WW];
        const float l2 = fl[g + 2 * (size_t)HH * WW];
        const float l3 = fl[g + 3 * (size_t)HH * WW];
        float cost[MAXD];
        float m = 1e30f;
#pragma unroll
        for (int d = 0; d < MAXD; ++d) {
            const int xi = x - d + MAXD - 1;    // >= 0 always
            const float cv = fabsf(l0 - sR[r][0][xi]) + fabsf(l1 - sR[r][1][xi])
                           + fabsf(l2 - sR[r][2][xi]) + fabsf(l3 - sR[r][3][xi]);
            cost[d] = cv;
            m = fminf(m, cv);
        }
        float s = 0.0f, wsum = 0.0f;
#pragma unroll
        for (int d = 0; d < MAXD; ++d) {
            const float p = __expf(m - cost[d]);   // softmax(-cost), min-stabilized
            s += p;
            wsum += p * (float)d;
        }
        sP[r][x] = 8.0f * (wsum / s);              // * img_h / h = 1024/128
    }
    __syncthreads();

    // Phase 3: x-interpolate both pred rows to width OW (amortized over ~8 oy).
    const float sxf = (float)(WW - 1) / (float)(OW - 1);   // 239/1919
    for (int i = tid; i < 2 * OW; i += 256) {
        const int r = i / OW;
        const int ox = i - r * OW;
        const float xsf = (float)ox * sxf;
        int x0 = (int)xsf;
        if (x0 > WW - 1) x0 = WW - 1;
        const int x1 = min(x0 + 1, WW - 1);
        const float wx = xsf - (float)x0;
        const float a = sP[r][x0];
        vx[r][ox] = a + (sP[r][x1] - a) * wx;
    }
    __syncthreads();

    // Phase 4: y-interpolate + coalesced float4 stores for the oy rows owned
    // by this block (floor(oy*sy) == y0; each oy claimed by exactly one block).
    const float syf = (float)(HH - 1) / (float)(OH - 1);   // 127/1023
    const int base = (int)((float)y0 * ((float)(OH - 1) / (float)(HH - 1))) - 2;
    const float4* __restrict__ v0p = (const float4*)vx[0];
    const float4* __restrict__ v1p = (const float4*)vx[1];
    for (int k = 0; k < 13; ++k) {
        const int oy = base + k;
        if (oy < 0 || oy >= OH) continue;                  // wave-uniform
        const float ysf = (float)oy * syf;
        int yy = (int)ysf;
        if (yy > HH - 1) yy = HH - 1;
        if (yy != y0) continue;                            // wave-uniform
        const float wy = ysf - (float)yy;
        float4* __restrict__ orow = (float4*)(out + ((size_t)b * OH + oy) * OW);
        for (int q = tid; q < OW / 4; q += 256) {
            const float4 v0 = v0p[q];
            const float4 v1 = v1p[q];
            float4 o;
            o.x = v0.x + (v1.x - v0.x) * wy;
            o.y = v0.y + (v1.y - v0.y) * wy;
            o.z = v0.z + (v1.z - v0.z) * wy;
            o.w = v0.w + (v1.w - v0.w) * wy;
            orow[q] = o;
        }
    }
}

extern "C" void kernel_launch(void* const* d_in, const int* in_sizes, int n_in,
                              void* d_out, int out_size, void* d_ws, size_t ws_size,
                              hipStream_t stream) {
    const float* feat_l = (const float*)d_in[0];
    const float* feat_r = (const float*)d_in[1];
    float* out = (float*)d_out;
    fused_kernel<<<BB * HH, 256, 0, stream>>>(feat_l, feat_r, out);
}

// Round 3
// 148.171 us; speedup vs baseline: 1.0345x; 1.0345x over previous
//
#include <hip/hip_runtime.h>
#include <math.h>

// Problem constants: feat (B=16, C=4, h=128, w=240), MAX_DISP=24,
// output (B,1,1024,1920) fp32.
#define BB 16
#define CC 4
#define HH 128
#define WW 240
#define MAXD 24
#define OH 1024
#define OW 1920

// Fused: cost volume + softmax-expectation + x8 + bilinear align-corners resize.
// One block per (b, y0): computes pred rows y0 and y0+1, x-interpolates both to
// width 1920 in LDS, then writes the ~8 output rows whose floor(oy*sy) == y0.
// LDS: vx unions over dead sR -> 17.3 KB total; 2048 blocks = 8/CU, all
// co-resident in one dispatch wave.
__global__ __launch_bounds__(256) void fused_kernel(const float* __restrict__ fl,
                                                    const float* __restrict__ fr,
                                                    float* __restrict__ out) {
    const int blk = blockIdx.x;           // b*HH + y0
    const int b = blk >> 7;
    const int y0 = blk & (HH - 1);
    const int y1 = min(y0 + 1, HH - 1);
    const int tid = threadIdx.x;

    __shared__ union {
        float sR[2][CC][WW + MAXD - 1];   // phases 1-2 (zero-padded left by 23)
        float vx[2][OW];                  // phases 3-4 (sR dead by then)
    } u;
    __shared__ float sP[2][WW];           // pred rows (already x8 scaled)

    const int rows2[2] = {y0, y1};

    // Prefetch this thread's left-feature values (phase-2 inputs) so the
    // global-load latency overlaps the LDS staging below.
    float lv[2][CC];
    #pragma unroll
    for (int t = 0; t < 2; ++t) {
        const int j = tid + t * 256;
        if (j < 2 * WW) {
            const int r = j / WW;
            const int x = j - r * WW;
            const size_t g = (((size_t)b * CC) * HH + rows2[r]) * WW + x;
            #pragma unroll
            for (int c = 0; c < CC; ++c)
                lv[t][c] = fl[g + (size_t)c * HH * WW];
        }
    }

    // Phase 1: stage right-feature rows into LDS (zero left pad).
    for (int i = tid; i < 2 * CC * WW; i += 256) {
        const int r = i / (CC * WW);
        const int rem = i - r * (CC * WW);
        const int c = rem / WW;
        const int x = rem - c * WW;
        u.sR[r][c][x + MAXD - 1] = fr[(((size_t)b * CC + c) * HH + rows2[r]) * WW + x];
    }
    for (int i = tid; i < 2 * CC * (MAXD - 1); i += 256) {
        const int r = i / (CC * (MAXD - 1));
        const int rem = i - r * (CC * (MAXD - 1));
        const int c = rem / (MAXD - 1);
        const int x = rem - c * (MAXD - 1);
        u.sR[r][c][x] = 0.0f;
    }
    __syncthreads();

    // Phase 2: pred rows (cost volume + min-stabilized softmax expectation, x8).
    #pragma unroll
    for (int t = 0; t < 2; ++t) {
        const int j = tid + t * 256;
        if (j >= 2 * WW) break;
        const int r = j / WW;
        const int x = j - r * WW;
        float cost[MAXD];
        float m = 1e30f;
#pragma unroll
        for (int d = 0; d < MAXD; ++d) {
            const int xi = x - d + MAXD - 1;    // >= 0 always
            const float cv = fabsf(lv[t][0] - u.sR[r][0][xi])
                           + fabsf(lv[t][1] - u.sR[r][1][xi])
                           + fabsf(lv[t][2] - u.sR[r][2][xi])
                           + fabsf(lv[t][3] - u.sR[r][3][xi]);
            cost[d] = cv;
            m = fminf(m, cv);
        }
        float s = 0.0f, wsum = 0.0f;
#pragma unroll
        for (int d = 0; d < MAXD; ++d) {
            const float p = __expf(m - cost[d]);   // softmax(-cost)
            s += p;
            wsum += p * (float)d;
        }
        sP[r][x] = 8.0f * (wsum / s);              // * img_h / h = 1024/128
    }
    __syncthreads();

    // Phase 3: x-interpolate both pred rows to width OW (sR now dead; vx
    // overlays it — reads only sP, so the union is safe after the barrier).
    const float sxf = (float)(WW - 1) / (float)(OW - 1);   // 239/1919
    for (int i = tid; i < 2 * OW; i += 256) {
        const int r = i / OW;
        const int ox = i - r * OW;
        const float xsf = (float)ox * sxf;
        int x0 = (int)xsf;
        if (x0 > WW - 1) x0 = WW - 1;
        const int x1 = min(x0 + 1, WW - 1);
        const float wx = xsf - (float)x0;
        const float a = sP[r][x0];
        u.vx[r][ox] = a + (sP[r][x1] - a) * wx;
    }
    __syncthreads();

    // Phase 4: y-interpolate + coalesced float4 stores for the oy rows owned
    // by this block (floor(oy*sy) == y0; each oy claimed by exactly one block).
    const float syf = (float)(HH - 1) / (float)(OH - 1);   // 127/1023
    const int base = (int)((float)y0 * ((float)(OH - 1) / (float)(HH - 1))) - 2;
    const float4* __restrict__ v0p = (const float4*)u.vx[0];
    const float4* __restrict__ v1p = (const float4*)u.vx[1];
    for (int k = 0; k < 13; ++k) {
        const int oy = base + k;
        if (oy < 0 || oy >= OH) continue;                  // wave-uniform
        const float ysf = (float)oy * syf;
        int yy = (int)ysf;
        if (yy > HH - 1) yy = HH - 1;
        if (yy != y0) continue;                            // wave-uniform
        const float wy = ysf - (float)yy;
        float4* __restrict__ orow = (float4*)(out + ((size_t)b * OH + oy) * OW);
        for (int q = tid; q < OW / 4; q += 256) {
            const float4 v0 = v0p[q];
            const float4 v1 = v1p[q];
            float4 o;
            o.x = v0.x + (v1.x - v0.x) * wy;
            o.y = v0.y + (v1.y - v0.y) * wy;
            o.z = v0.z + (v1.z - v0.z) * wy;
            o.w = v0.w + (v1.w - v0.w) * wy;
            orow[q] = o;
        }
    }
}

extern "C" void kernel_launch(void* const* d_in, const int* in_sizes, int n_in,
                              void* d_out, int out_size, void* d_ws, size_t ws_size,
                              hipStream_t stream) {
    const float* feat_l = (const float*)d_in[0];
    const float* feat_r = (const float*)d_in[1];
    float* out = (float*)d_out;
    fused_kernel<<<BB * HH, 256, 0, stream>>>(feat_l, feat_r, out);
}